// Round 6
// baseline (12.311 us; speedup 1.0000x reference)
//
#include <hip/hip_runtime.h>
#include <math.h>

// Closed form (derived R2, verified vs full statevector sim in R1):
//   e0 = e2 = e3 = 0;  e1 = -cos^2(1) * cos(pi/2 * w1),  w1 = in[:,4].
//
// R6 = R5 with the compile fix: native ext_vector type for the nontemporal
// float4 store (HIP_vector_type is rejected by __builtin_nontemporal_store).
//   - 4 independent scalar loads in flight per thread (latency/MLP attack)
//   - stores lane-contiguous per instruction
//   - nontemporal on both streams (read-once/write-once, 37MB > 32MB L2)
#define NBLK 1024
#define NTHR 256

typedef float floatx4 __attribute__((ext_vector_type(4)));

__global__ __launch_bounds__(NTHR) void qlayer_kernel(
    const float* __restrict__ in, floatx4* __restrict__ out4, int B)
{
    const int gtid = blockIdx.x * NTHR + threadIdx.x;
    const int stride = NBLK * NTHR;          // 262144 threads total
    const float k = 1.5707963267948966f;     // pi/2
    const float A = -0.2919265817264289f;    // -cos^2(1)

    for (int base = 0; base < B; base += 4 * stride) {
        const int r0 = base + gtid;
        if (r0 + 3 * stride < B) {
            // fast path: 4 independent loads in flight before any use
            const float wa = __builtin_nontemporal_load(&in[5 * (r0 + 0 * stride) + 4]);
            const float wb = __builtin_nontemporal_load(&in[5 * (r0 + 1 * stride) + 4]);
            const float wc = __builtin_nontemporal_load(&in[5 * (r0 + 2 * stride) + 4]);
            const float wd = __builtin_nontemporal_load(&in[5 * (r0 + 3 * stride) + 4]);
            floatx4 oa = {0.f, A * __cosf(k * wa), 0.f, 0.f};
            floatx4 ob = {0.f, A * __cosf(k * wb), 0.f, 0.f};
            floatx4 oc = {0.f, A * __cosf(k * wc), 0.f, 0.f};
            floatx4 od = {0.f, A * __cosf(k * wd), 0.f, 0.f};
            __builtin_nontemporal_store(oa, &out4[r0 + 0 * stride]);
            __builtin_nontemporal_store(ob, &out4[r0 + 1 * stride]);
            __builtin_nontemporal_store(oc, &out4[r0 + 2 * stride]);
            __builtin_nontemporal_store(od, &out4[r0 + 3 * stride]);
        } else {
#pragma unroll
            for (int c = 0; c < 4; ++c) {
                const int r = r0 + c * stride;
                if (r < B) {
                    const float w = in[5 * r + 4];
                    floatx4 o = {0.f, A * __cosf(k * w), 0.f, 0.f};
                    __builtin_nontemporal_store(o, &out4[r]);
                }
            }
        }
    }
}

extern "C" void kernel_launch(void* const* d_in, const int* in_sizes, int n_in,
                              void* d_out, int out_size, void* d_ws, size_t ws_size,
                              hipStream_t stream) {
    const float* in = (const float*)d_in[0];
    floatx4* out4 = (floatx4*)d_out;
    const int B = in_sizes[0] / 5;  // (B,5) float32; 1048576 = 4*NBLK*NTHR exactly
    qlayer_kernel<<<NBLK, NTHR, 0, stream>>>(in, out4, B);
}

// Round 7
// 9.823 us; speedup vs baseline: 1.2533x; 1.2533x over previous
//
#include <hip/hip_runtime.h>
#include <math.h>

// Closed form (derived R2, verified vs full statevector sim in R1):
//   e0 = e2 = e3 = 0;  e1 = -cos^2(1) * cos(pi/2 * w1),  w1 = in[:,4].
//
// R7 = R2 (best so far, 10.4us) + ONE change: nontemporal float4 stores.
//   - 1 row/thread, 4096x256 = 1M threads (max TLP; R6 proved TLP > ILP)
//   - loads stay cached (L1 line-sharing across adjacent lanes is load-bearing)
//   - stores are write-once -> NT skips L2 write-allocate
typedef float floatx4 __attribute__((ext_vector_type(4)));

__global__ __launch_bounds__(256) void qlayer_kernel(
    const float* __restrict__ in, floatx4* __restrict__ out4, int B)
{
    int b = blockIdx.x * blockDim.x + threadIdx.x;
    if (b >= B) return;

    const float w1 = in[5 * b + 4];
    const float c = __cosf(1.5707963267948966f * w1);      // w1 in [0,1)
    const float e1 = -0.2919265817264289f * c;             // -cos^2(1) * c

    floatx4 o = {0.0f, e1, 0.0f, 0.0f};
    __builtin_nontemporal_store(o, &out4[b]);
}

extern "C" void kernel_launch(void* const* d_in, const int* in_sizes, int n_in,
                              void* d_out, int out_size, void* d_ws, size_t ws_size,
                              hipStream_t stream) {
    const float* in = (const float*)d_in[0];
    floatx4* out4 = (floatx4*)d_out;
    const int B = in_sizes[0] / 5;  // (B,5) float32
    const int block = 256;
    const int grid = (B + block - 1) / block;
    qlayer_kernel<<<grid, block, 0, stream>>>(in, out4, B);
}